// Round 2
// 74.893 us; speedup vs baseline: 1.0184x; 1.0184x over previous
//
#include <hip/hip_runtime.h>
#include <math.h>

// DiscreteBayesianFlow: probs = softmax(beta*(K*onehot(x)-1) + sqrt(beta)*(noise @ L0^T))
// L0 = chol((K+0.001)I - 11^T), diag-plus-rank-one closed form:
//   t_j = d/(j-d), a_j = sqrt(d + t_j), b_j = t_j/a_j, d = K+0.001
// => (noise @ L0^T)_j = prefix_{k<j}(noise_k*b_k) + noise_j*a_j  -- O(K) wave scan.
// All cross-lane ops via GCN DPP (pure VALU, no LDS pipe / lgkmcnt latency).
//
// R1 changes vs 76.6us baseline (resubmitted R2 after container-infra failure):
//  - f64 setup -> well-conditioned f32: d+t_j = d*(j+1-d)/(j-d) avoids the
//    j=255 cancellation, so plain f32 div/sqrt carries ~1e-7 rel err.
//    Kills ~400-600 cycles of half-rate f64 div/sqrt sequences per wave.
//  - LOG2E folded into beta/sb (exp(l-m) == exp2(l'-m') with l'=l*LOG2E):
//    saves 4 muls/row, numerically identical softmax.
//  - branch-free double-row body (store predicated only) so the two rows'
//    serial DPP chains interleave for ILP.

#define ROWS_PER_WAVE 2

template<int CTRL, int RM>
__device__ __forceinline__ float dpp_f(float oldv, float x) {
    return __int_as_float(__builtin_amdgcn_update_dpp(
        __float_as_int(oldv), __float_as_int(x), CTRL, RM, 0xF, false));
}

// inclusive prefix-sum across the 64-lane wave (row_shr tree + row_bcast)
__device__ __forceinline__ float wave_iscan_add(float x) {
    x += dpp_f<0x111, 0xF>(0.0f, x);   // row_shr:1
    x += dpp_f<0x112, 0xF>(0.0f, x);   // row_shr:2
    x += dpp_f<0x114, 0xF>(0.0f, x);   // row_shr:4
    x += dpp_f<0x118, 0xF>(0.0f, x);   // row_shr:8
    x += dpp_f<0x142, 0xA>(0.0f, x);   // row_bcast:15 -> rows 1,3
    x += dpp_f<0x143, 0xC>(0.0f, x);   // row_bcast:31 -> rows 2,3
    return x;
}

__device__ __forceinline__ float wave_bcast_sum(float x) {
    x = wave_iscan_add(x);
    return __int_as_float(__builtin_amdgcn_readlane(__float_as_int(x), 63));
}

__device__ __forceinline__ float wave_bcast_max(float x) {
    // old = own value (identity for max); invalid/masked lanes contribute self
    x = fmaxf(x, dpp_f<0x111, 0xF>(x, x));
    x = fmaxf(x, dpp_f<0x112, 0xF>(x, x));
    x = fmaxf(x, dpp_f<0x114, 0xF>(x, x));
    x = fmaxf(x, dpp_f<0x118, 0xF>(x, x));
    x = fmaxf(x, dpp_f<0x142, 0xA>(x, x));
    x = fmaxf(x, dpp_f<0x143, 0xC>(x, x));
    return __int_as_float(__builtin_amdgcn_readlane(__float_as_int(x), 63));
}

__global__ __launch_bounds__(256) void dbf_kernel(
    const int* __restrict__ data,
    const float* __restrict__ t,
    const float4* __restrict__ noise4,
    float4* __restrict__ out4,
    int n_rows)
{
    const int lane = threadIdx.x & 63;
    const int wave = threadIdx.x >> 6;
    const int row0 = (blockIdx.x * 4 + wave) * ROWS_PER_WAVE;
    if (row0 >= n_rows) return;

    // Closed-form Cholesky coefficients, f32, well-conditioned:
    //   t_j = d/(j-d);  d + t_j = d*(j+1-d)/(j-d) = t_j*(j+1-d)  (no cancellation)
    //   a_j = sqrt(t_j*n1);  b_j = t_j/a_j
    float av[4], bv[4];
    #pragma unroll
    for (int i = 0; i < 4; ++i) {
        const float jf = (float)(lane * 4 + i);
        const float n0 = (jf - 256.0f) - 0.001f;   // j - d    (exact-to-rounding)
        const float n1 = (jf - 255.0f) - 0.001f;   // j+1 - d  (exact at j=255: -0.001)
        const float tk = 256.001f / n0;            // t_j  (negative)
        const float a  = sqrtf(tk * n1);           // sqrt(d + t_j), well-conditioned
        av[i] = a;
        bv[i] = tk / a;
    }

    // issue all global loads up front (ROWS_PER_WAVE independent chains)
    float4 nz[ROWS_PER_WAVE];
    float  tt[ROWS_PER_WAVE];
    int    xx[ROWS_PER_WAVE];
    bool   ok[ROWS_PER_WAVE];
    #pragma unroll
    for (int r = 0; r < ROWS_PER_WAVE; ++r) {
        const int row = row0 + r;
        ok[r] = (row < n_rows);
        const int rr = ok[r] ? row : 0;
        nz[r] = noise4[(size_t)rr * 64 + lane];
        tt[r] = t[rr];
        xx[r] = data[rr];
    }

    // branch-free compute for both rows (garbage for !ok rows, store predicated)
    float4 res[ROWS_PER_WAVE];
    #pragma unroll
    for (int r = 0; r < ROWS_PER_WAVE; ++r) {
        const float w0 = nz[r].x * bv[0];
        const float w1 = nz[r].y * bv[1];
        const float w2 = nz[r].z * bv[2];
        const float w3 = nz[r].w * bv[3];
        const float local = w0 + w1 + w2 + w3;
        const float base  = wave_iscan_add(local) - local;

        float sb = fminf(tt[r], 1.0f - 1e-6f);   // * MAX_SQRT_BETA (=1)
        const bool lo = sb < 1e-10f;
        sb = fmaxf(sb, 1e-10f);
        const float LOG2E = 1.4426950408889634f;
        const float bl = (sb * sb) * LOG2E;      // beta, pre-scaled to log2 domain
        const float sl = sb * LOG2E;             // sqrt(beta), pre-scaled
        const int x = xx[r];
        const int j0 = lane * 4;

        // logits already in log2 domain: softmax(l) == exp2(l'-m')/sum
        float l0 = bl * (256.0f * (float)(j0 + 0 == x) - 1.0f) + sl * (base + nz[r].x * av[0]);
        float l1 = bl * (256.0f * (float)(j0 + 1 == x) - 1.0f) + sl * (base + w0 + nz[r].y * av[1]);
        float l2 = bl * (256.0f * (float)(j0 + 2 == x) - 1.0f) + sl * (base + w0 + w1 + nz[r].z * av[2]);
        float l3 = bl * (256.0f * (float)(j0 + 3 == x) - 1.0f) + sl * (base + w0 + w1 + w2 + nz[r].w * av[3]);

        const float m = wave_bcast_max(fmaxf(fmaxf(l0, l1), fmaxf(l2, l3)));

        const float e0 = exp2f(l0 - m);
        const float e1 = exp2f(l1 - m);
        const float e2 = exp2f(l2 - m);
        const float e3 = exp2f(l3 - m);
        const float s = wave_bcast_sum(e0 + e1 + e2 + e3);
        const float inv = 1.0f / s;

        float4 o;
        if (lo) {
            const float u = 1.0f / 256.0f;
            o.x = u; o.y = u; o.z = u; o.w = u;
        } else {
            o.x = e0 * inv; o.y = e1 * inv; o.z = e2 * inv; o.w = e3 * inv;
        }
        res[r] = o;
    }

    #pragma unroll
    for (int r = 0; r < ROWS_PER_WAVE; ++r) {
        if (ok[r]) out4[(size_t)(row0 + r) * 64 + lane] = res[r];
    }
}

extern "C" void kernel_launch(void* const* d_in, const int* in_sizes, int n_in,
                              void* d_out, int out_size, void* d_ws, size_t ws_size,
                              hipStream_t stream) {
    const int*    data   = (const int*)d_in[0];
    const float*  t      = (const float*)d_in[1];
    const float4* noise4 = (const float4*)d_in[2];
    float4*       out4   = (float4*)d_out;

    const int n_rows = in_sizes[1];                       // B*S
    const int rows_per_block = 4 * ROWS_PER_WAVE;         // 4 waves/block
    const int blocks = (n_rows + rows_per_block - 1) / rows_per_block;
    dbf_kernel<<<blocks, 256, 0, stream>>>(data, t, noise4, out4, n_rows);
}